// Round 1
// baseline (441.469 us; speedup 1.0000x reference)
//
#include <hip/hip_runtime.h>
#include <math.h>

#define DDIM 1024
#define HHD  64
#define NH   16
#define BB   2
#define CTX  2048
#define MROWS (BB*CTX)   // 4096
#define D3   (3*DDIM)    // 3072
#define DF   (4*DDIM)    // 4096

using bf16x8 = __attribute__((ext_vector_type(8))) short;
using f32x4  = __attribute__((ext_vector_type(4))) float;
using u16x4  = __attribute__((ext_vector_type(4))) unsigned short;

__device__ __forceinline__ unsigned short f2bf(float f) {
  union { float f; unsigned u; } c; c.f = f;
  unsigned u = c.u;
  return (unsigned short)((u + 0x7FFFu + ((u >> 16) & 1u)) >> 16);
}

// ---------------- elementwise fp32 -> bf16 ----------------
__global__ void k_cvt_bf16(const float* __restrict__ in, unsigned short* __restrict__ out, int n4) {
  int i = blockIdx.x * blockDim.x + threadIdx.x;
  if (i >= n4) return;
  float4 v = reinterpret_cast<const float4*>(in)[i];
  u16x4 o;
  o[0] = f2bf(v.x); o[1] = f2bf(v.y); o[2] = f2bf(v.z); o[3] = f2bf(v.w);
  reinterpret_cast<u16x4*>(out)[i] = o;
}

// ---------------- transpose fp32 [R][Cn] -> bf16 [Cn][R] ----------------
__global__ void k_transpose_w(const float* __restrict__ in, unsigned short* __restrict__ out,
                              int R, int Cn) {
  __shared__ float tile[32][33];
  int c0 = blockIdx.x * 32, r0 = blockIdx.y * 32;
  int t = threadIdx.x, tr = t >> 5, tc = t & 31;
#pragma unroll
  for (int i = 0; i < 4; ++i)
    tile[tr + i*8][tc] = in[(size_t)(r0 + tr + i*8) * Cn + (c0 + tc)];
  __syncthreads();
#pragma unroll
  for (int i = 0; i < 4; ++i)
    out[(size_t)(c0 + tr + i*8) * R + (r0 + tc)] = f2bf(tile[tc][tr + i*8]);
}

// ------------- per-head bf16 transpose [CTX][HHD] -> [HHD][CTX] -------------
__global__ void k_transpose_v(const unsigned short* __restrict__ in, unsigned short* __restrict__ out) {
  __shared__ unsigned short tile[32][33];
  int head = blockIdx.z;
  int d0 = blockIdx.x * 32, c0 = blockIdx.y * 32;
  int t = threadIdx.x, tr = t >> 5, tc = t & 31;
  const unsigned short* ip = in + (size_t)head * CTX * HHD;
  unsigned short* op = out + (size_t)head * CTX * HHD;
#pragma unroll
  for (int i = 0; i < 4; ++i)
    tile[tr + i*8][tc] = ip[(c0 + tr + i*8) * HHD + (d0 + tc)];
  __syncthreads();
#pragma unroll
  for (int i = 0; i < 4; ++i)
    op[(d0 + tr + i*8) * CTX + (c0 + tc)] = tile[tc][tr + i*8];
}

// ---------------- GEMM: C[M][N] = A[M][K](bf16) * Bt[N][K]^T(bf16) + bias ----------------
// EPI 0: scatter qkv -> Q/K/V [b,h,c,d] bf16
// EPI 1: outf = acc + bias + res (fp32)
// EPI 2: outb = bf16(gelu_exact(acc + bias))
template<int EPI>
__launch_bounds__(256, 2)
__global__ void k_gemm_bt(const unsigned short* __restrict__ A,
                          const unsigned short* __restrict__ Bt,
                          const float* __restrict__ bias,
                          const float* __restrict__ res,
                          float* __restrict__ outf,
                          unsigned short* __restrict__ outb,
                          unsigned short* __restrict__ outQ,
                          unsigned short* __restrict__ outK,
                          unsigned short* __restrict__ outV,
                          int Ndim, int Kdim) {
  __shared__ __align__(16) unsigned short As[128*32];
  __shared__ __align__(16) unsigned short Bs[128*32];
  const int m0 = blockIdx.y * 128, n0 = blockIdx.x * 128;
  const int t = threadIdx.x;
  const int w = t >> 6, lane = t & 63, lr = lane & 15, lg = lane >> 4;
  const int wr = (w >> 1) * 64, wc = (w & 1) * 64;

  f32x4 acc[4][4];
#pragma unroll
  for (int i = 0; i < 4; ++i)
#pragma unroll
    for (int j = 0; j < 4; ++j) acc[i][j] = f32x4{0.f, 0.f, 0.f, 0.f};

  const int idx0 = t, idx1 = 256 + t;
  const unsigned short* Ar0 = A  + (size_t)(m0 + (idx0 >> 2)) * Kdim + (idx0 & 3) * 8;
  const unsigned short* Ar1 = A  + (size_t)(m0 + (idx1 >> 2)) * Kdim + (idx1 & 3) * 8;
  const unsigned short* Br0 = Bt + (size_t)(n0 + (idx0 >> 2)) * Kdim + (idx0 & 3) * 8;
  const unsigned short* Br1 = Bt + (size_t)(n0 + (idx1 >> 2)) * Kdim + (idx1 & 3) * 8;

  uint4 ra0 = *(const uint4*)(Ar0);
  uint4 ra1 = *(const uint4*)(Ar1);
  uint4 rb0 = *(const uint4*)(Br0);
  uint4 rb1 = *(const uint4*)(Br1);

  const int nk = Kdim >> 5;
  for (int kk = 0; kk < nk; ++kk) {
    *(uint4*)&As[idx0 * 8] = ra0;
    *(uint4*)&As[idx1 * 8] = ra1;
    *(uint4*)&Bs[idx0 * 8] = rb0;
    *(uint4*)&Bs[idx1 * 8] = rb1;
    __syncthreads();
    if (kk + 1 < nk) {
      int ko = (kk + 1) * 32;
      ra0 = *(const uint4*)(Ar0 + ko);
      ra1 = *(const uint4*)(Ar1 + ko);
      rb0 = *(const uint4*)(Br0 + ko);
      rb1 = *(const uint4*)(Br1 + ko);
    }
    bf16x8 af[4], bfr[4];
#pragma unroll
    for (int mi = 0; mi < 4; ++mi)
      af[mi] = *(const bf16x8*)&As[(wr + mi*16 + lr) * 32 + lg * 8];
#pragma unroll
    for (int ni = 0; ni < 4; ++ni)
      bfr[ni] = *(const bf16x8*)&Bs[(wc + ni*16 + lr) * 32 + lg * 8];
#pragma unroll
    for (int mi = 0; mi < 4; ++mi)
#pragma unroll
      for (int ni = 0; ni < 4; ++ni)
        acc[mi][ni] = __builtin_amdgcn_mfma_f32_16x16x32_bf16(af[mi], bfr[ni], acc[mi][ni], 0, 0, 0);
    __syncthreads();
  }

#pragma unroll
  for (int mi = 0; mi < 4; ++mi) {
#pragma unroll
    for (int r = 0; r < 4; ++r) {
      int row = m0 + wr + mi*16 + lg*4 + r;
#pragma unroll
      for (int ni = 0; ni < 4; ++ni) {
        int col = n0 + wc + ni*16 + lr;
        float v = acc[mi][ni][r] + bias[col];
        if constexpr (EPI == 0) {
          int b = row >> 11, c = row & 2047;
          int sec = col >> 10, nn = col & 1023;
          int h = nn >> 6, d = nn & 63;
          size_t o = ((size_t)(b * NH + h) * CTX + c) * HHD + d;
          unsigned short bv = f2bf(v);
          if (sec == 0) outQ[o] = bv;
          else if (sec == 1) outK[o] = bv;
          else outV[o] = bv;
        } else if constexpr (EPI == 1) {
          size_t o = (size_t)row * Ndim + col;
          outf[o] = v + res[o];
        } else {
          float g = 0.5f * v * (1.0f + erff(v * 0.70710678118654752f));
          outb[(size_t)row * Ndim + col] = f2bf(g);
        }
      }
    }
  }
}

// ---------------- flash attention ----------------
// grid: BB*NH*(CTX/64); block 256 (4 waves); each wave one 16-row Q tile
__launch_bounds__(256, 2)
__global__ void k_attn(const unsigned short* __restrict__ Qb,
                       const unsigned short* __restrict__ Kb,
                       const unsigned short* __restrict__ Vt,
                       unsigned short* __restrict__ A2) {
  __shared__ __align__(16) unsigned short pls[4][16 * 64];
  const int blk = blockIdx.x;
  const int bh = blk >> 5;        // CTX/64 = 32 q-tiles per (b,h)
  const int qt = blk & 31;
  const int b = bh >> 4, h = bh & 15;
  const int t = threadIdx.x, w = t >> 6, lane = t & 63, lr = lane & 15, lg = lane >> 4;
  const int qbase = qt * 64 + w * 16;
  const unsigned short* Qh = Qb + (size_t)bh * CTX * HHD;
  const unsigned short* Kh = Kb + (size_t)bh * CTX * HHD;
  const unsigned short* Vh = Vt + (size_t)bh * CTX * HHD;
  unsigned short* pw = pls[w];

  bf16x8 aq[2];
#pragma unroll
  for (int kc = 0; kc < 2; ++kc)
    aq[kc] = *(const bf16x8*)(Qh + (qbase + lr) * HHD + kc * 32 + lg * 8);

  float mrun[4], lrun[4];
  f32x4 oacc[4];
#pragma unroll
  for (int r = 0; r < 4; ++r) { mrun[r] = -1e30f; lrun[r] = 0.f; }
#pragma unroll
  for (int nt = 0; nt < 4; ++nt) oacc[nt] = f32x4{0.f, 0.f, 0.f, 0.f};

  for (int j0 = 0; j0 < CTX; j0 += 64) {
    f32x4 s[4];
#pragma unroll
    for (int nt = 0; nt < 4; ++nt) {
      s[nt] = f32x4{0.f, 0.f, 0.f, 0.f};
#pragma unroll
      for (int kc = 0; kc < 2; ++kc) {
        bf16x8 bk = *(const bf16x8*)(Kh + (j0 + nt*16 + lr) * HHD + kc * 32 + lg * 8);
        s[nt] = __builtin_amdgcn_mfma_f32_16x16x32_bf16(aq[kc], bk, s[nt], 0, 0, 0);
      }
    }
#pragma unroll
    for (int nt = 0; nt < 4; ++nt) s[nt] *= 0.125f;   // 1/sqrt(64)

    float alpha[4];
#pragma unroll
    for (int r = 0; r < 4; ++r) {
      float m = fmaxf(fmaxf(s[0][r], s[1][r]), fmaxf(s[2][r], s[3][r]));
#pragma unroll
      for (int off = 1; off < 16; off <<= 1) m = fmaxf(m, __shfl_xor(m, off));
      float mn = fmaxf(mrun[r], m);
      alpha[r] = __expf(mrun[r] - mn);
      mrun[r] = mn;
      float p0 = __expf(s[0][r] - mn), p1 = __expf(s[1][r] - mn);
      float p2 = __expf(s[2][r] - mn), p3 = __expf(s[3][r] - mn);
      s[0][r] = p0; s[1][r] = p1; s[2][r] = p2; s[3][r] = p3;
      float sum = p0 + p1 + p2 + p3;
#pragma unroll
      for (int off = 1; off < 16; off <<= 1) sum += __shfl_xor(sum, off);
      lrun[r] = lrun[r] * alpha[r] + sum;
    }
#pragma unroll
    for (int nt = 0; nt < 4; ++nt)
#pragma unroll
      for (int r = 0; r < 4; ++r) oacc[nt][r] *= alpha[r];

    // P -> LDS (bf16, XOR-swizzled 16B granules)
#pragma unroll
    for (int nt = 0; nt < 4; ++nt) {
#pragma unroll
      for (int r = 0; r < 4; ++r) {
        int row = lg * 4 + r, col = nt * 16 + lr;
        int g2 = (col >> 3) ^ (row & 7);
        pw[row * 64 + g2 * 8 + (col & 7)] = f2bf(s[nt][r]);
      }
    }
    bf16x8 pa[2];
#pragma unroll
    for (int kc = 0; kc < 2; ++kc) {
      int g2 = (kc * 4 + lg) ^ (lr & 7);
      pa[kc] = *(const bf16x8*)&pw[lr * 64 + g2 * 8];
    }
#pragma unroll
    for (int nt = 0; nt < 4; ++nt) {
#pragma unroll
      for (int kc = 0; kc < 2; ++kc) {
        bf16x8 bv = *(const bf16x8*)(Vh + (nt*16 + lr) * CTX + j0 + kc * 32 + lg * 8);
        oacc[nt] = __builtin_amdgcn_mfma_f32_16x16x32_bf16(pa[kc], bv, oacc[nt], 0, 0, 0);
      }
    }
  }

#pragma unroll
  for (int r = 0; r < 4; ++r) {
    float rinv = 1.0f / lrun[r];
    int row = qbase + lg * 4 + r;
#pragma unroll
    for (int nt = 0; nt < 4; ++nt) {
      int d = nt * 16 + lr;
      A2[(size_t)(b * CTX + row) * DDIM + h * HHD + d] = f2bf(oacc[nt][r] * rinv);
    }
  }
}

// ---------------- LayerNorm (ddof=1) ----------------
template<bool WB>
__global__ void k_ln(const float* __restrict__ in, const float* __restrict__ gamma,
                     const float* __restrict__ beta, float* __restrict__ outf,
                     unsigned short* __restrict__ outb) {
  const int row = blockIdx.x, t = threadIdx.x;
  const float* x = in + (size_t)row * DDIM;
  float v[4]; float s = 0.f, sq = 0.f;
#pragma unroll
  for (int i = 0; i < 4; ++i) { v[i] = x[t + i*256]; s += v[i]; sq += v[i]*v[i]; }
#pragma unroll
  for (int off = 1; off < 64; off <<= 1) { s += __shfl_xor(s, off); sq += __shfl_xor(sq, off); }
  __shared__ float red[2][4];
  int w = t >> 6;
  if ((t & 63) == 0) { red[0][w] = s; red[1][w] = sq; }
  __syncthreads();
  s  = red[0][0] + red[0][1] + red[0][2] + red[0][3];
  sq = red[1][0] + red[1][1] + red[1][2] + red[1][3];
  float mean = s * (1.0f / DDIM);
  float var  = (sq - s * mean) * (1.0f / (DDIM - 1));
  float rstd = rsqrtf(var + 1e-5f);
#pragma unroll
  for (int i = 0; i < 4; ++i) {
    int c = t + i*256;
    float o = (v[i] - mean) * rstd * gamma[c] + beta[c];
    outf[(size_t)row * DDIM + c] = o;
    if constexpr (WB) outb[(size_t)row * DDIM + c] = f2bf(o);
  }
}

extern "C" void kernel_launch(void* const* d_in, const int* in_sizes, int n_in,
                              void* d_out, int out_size, void* d_ws, size_t ws_size,
                              hipStream_t stream) {
  const float* x      = (const float*)d_in[0];
  const float* w_qkv  = (const float*)d_in[1];
  const float* b_qkv  = (const float*)d_in[2];
  const float* w_out  = (const float*)d_in[3];
  const float* b_out  = (const float*)d_in[4];
  const float* w_ff1  = (const float*)d_in[5];
  const float* b_ff1  = (const float*)d_in[6];
  const float* w_ff2  = (const float*)d_in[7];
  const float* b_ff2  = (const float*)d_in[8];
  const float* gamma1 = (const float*)d_in[9];
  const float* beta1  = (const float*)d_in[10];
  const float* gamma2 = (const float*)d_in[11];
  const float* beta2  = (const float*)d_in[12];
  float* out = (float*)d_out;

  char* ws = (char*)d_ws;
  const size_t MB = 1024ull * 1024ull;
  unsigned short* Xb    = (unsigned short*)(ws + 0);        // 8 MB
  unsigned short* WqkvT = (unsigned short*)(ws + 8*MB);     // 6 MB
  unsigned short* WoutT = (unsigned short*)(ws + 14*MB);    // 2 MB
  unsigned short* Wff1T = (unsigned short*)(ws + 16*MB);    // 8 MB
  unsigned short* Wff2T = (unsigned short*)(ws + 24*MB);    // 8 MB
  unsigned short* Qb    = (unsigned short*)(ws + 32*MB);    // 8 MB
  unsigned short* Kb    = (unsigned short*)(ws + 40*MB);    // 8 MB
  unsigned short* Vt    = (unsigned short*)(ws + 48*MB);    // 8 MB
  unsigned short* A2    = (unsigned short*)(ws + 56*MB);    // 8 MB
  unsigned short* Vb    = (unsigned short*)(ws + 56*MB);    // aliases A2 (dead before attn writes)
  unsigned short* G     = (unsigned short*)(ws + 32*MB);    // 32 MB, reuses Qb..A2 after attn+G2
  float* y1             = (float*)(ws + 64*MB);             // 16 MB
  float* z              = (float*)(ws + 64*MB);             // aliases y1 (dead after LN1)
  float* h1f            = (float*)(ws + 80*MB);             // 16 MB
  unsigned short* h1b   = (unsigned short*)(ws + 96*MB);    // 8 MB  -> total 104 MB

  // bf16 conversions / weight transposes
  k_cvt_bf16<<<dim3(MROWS*DDIM/4/256), dim3(256), 0, stream>>>(x, Xb, MROWS*DDIM/4);
  k_transpose_w<<<dim3(D3/32,  DDIM/32), dim3(256), 0, stream>>>(w_qkv, WqkvT, DDIM, D3);
  k_transpose_w<<<dim3(DDIM/32, DDIM/32), dim3(256), 0, stream>>>(w_out, WoutT, DDIM, DDIM);
  k_transpose_w<<<dim3(DF/32,  DDIM/32), dim3(256), 0, stream>>>(w_ff1, Wff1T, DDIM, DF);
  k_transpose_w<<<dim3(DDIM/32, DF/32),  dim3(256), 0, stream>>>(w_ff2, Wff2T, DF, DDIM);

  // G1: qkv = Xb @ w_qkv + b_qkv  -> Q,K [b,h,c,d]; V -> Vb [b,h,c,d]
  k_gemm_bt<0><<<dim3(D3/128, MROWS/128), dim3(256), 0, stream>>>(
      Xb, WqkvT, b_qkv, nullptr, nullptr, nullptr, Qb, Kb, Vb, D3, DDIM);
  k_transpose_v<<<dim3(HHD/32, CTX/32, BB*NH), dim3(256), 0, stream>>>(Vb, Vt);

  k_attn<<<dim3(BB*NH*(CTX/64)), dim3(256), 0, stream>>>(Qb, Kb, Vt, A2);

  // G2: y1 = A2 @ w_out + b_out + x
  k_gemm_bt<1><<<dim3(DDIM/128, MROWS/128), dim3(256), 0, stream>>>(
      A2, WoutT, b_out, x, y1, nullptr, nullptr, nullptr, nullptr, DDIM, DDIM);
  k_ln<true><<<dim3(MROWS), dim3(256), 0, stream>>>(y1, gamma1, beta1, h1f, h1b);

  // G3: G = gelu(h1 @ w_ff1 + b_ff1) bf16
  k_gemm_bt<2><<<dim3(DF/128, MROWS/128), dim3(256), 0, stream>>>(
      h1b, Wff1T, b_ff1, nullptr, nullptr, G, nullptr, nullptr, nullptr, DF, DDIM);
  // G4: z = G @ w_ff2 + b_ff2 + h1
  k_gemm_bt<1><<<dim3(DDIM/128, MROWS/128), dim3(256), 0, stream>>>(
      G, Wff2T, b_ff2, h1f, z, nullptr, nullptr, nullptr, nullptr, DDIM, DF);
  k_ln<false><<<dim3(MROWS), dim3(256), 0, stream>>>(z, gamma2, beta2, out, nullptr);
}

// Round 2
// 303.147 us; speedup vs baseline: 1.4563x; 1.4563x over previous
//
#include <hip/hip_runtime.h>
#include <math.h>

#define DDIM 1024
#define HHD  64
#define NH   16
#define BB   2
#define CTX  2048
#define MROWS (BB*CTX)   // 4096
#define D3   (3*DDIM)    // 3072
#define DF   (4*DDIM)    // 4096

using bf16x8 = __attribute__((ext_vector_type(8))) short;
using f32x4  = __attribute__((ext_vector_type(4))) float;
using u16x4  = __attribute__((ext_vector_type(4))) unsigned short;

__device__ __forceinline__ unsigned short f2bf(float f) {
  union { float f; unsigned u; } c; c.f = f;
  unsigned u = c.u;
  return (unsigned short)((u + 0x7FFFu + ((u >> 16) & 1u)) >> 16);
}

// async global->LDS, 16B per lane. LDS dest must be wave-uniform-base + lane*16.
__device__ __forceinline__ void gload16(const void* g, void* l) {
  __builtin_amdgcn_global_load_lds(
      (const __attribute__((address_space(1))) unsigned int*)g,
      (__attribute__((address_space(3))) unsigned int*)l, 16, 0, 0);
}

// ---------------- elementwise fp32 -> bf16 ----------------
__global__ void k_cvt_bf16(const float* __restrict__ in, unsigned short* __restrict__ out, int n4) {
  int i = blockIdx.x * blockDim.x + threadIdx.x;
  if (i >= n4) return;
  float4 v = reinterpret_cast<const float4*>(in)[i];
  u16x4 o;
  o[0] = f2bf(v.x); o[1] = f2bf(v.y); o[2] = f2bf(v.z); o[3] = f2bf(v.w);
  reinterpret_cast<u16x4*>(out)[i] = o;
}

// ---------------- transpose fp32 [R][Cn] -> bf16 [Cn][R] ----------------
__global__ void k_transpose_w(const float* __restrict__ in, unsigned short* __restrict__ out,
                              int R, int Cn) {
  __shared__ float tile[32][33];
  int c0 = blockIdx.x * 32, r0 = blockIdx.y * 32;
  int t = threadIdx.x, tr = t >> 5, tc = t & 31;
#pragma unroll
  for (int i = 0; i < 4; ++i)
    tile[tr + i*8][tc] = in[(size_t)(r0 + tr + i*8) * Cn + (c0 + tc)];
  __syncthreads();
#pragma unroll
  for (int i = 0; i < 4; ++i)
    out[(size_t)(c0 + tr + i*8) * R + (r0 + tc)] = f2bf(tile[tc][tr + i*8]);
}

// ------------- per-head bf16 transpose [CTX][HHD] -> [HHD][CTX] -------------
__global__ void k_transpose_v(const unsigned short* __restrict__ in, unsigned short* __restrict__ out) {
  __shared__ unsigned short tile[32][33];
  int head = blockIdx.z;
  int d0 = blockIdx.x * 32, c0 = blockIdx.y * 32;
  int t = threadIdx.x, tr = t >> 5, tc = t & 31;
  const unsigned short* ip = in + (size_t)head * CTX * HHD;
  unsigned short* op = out + (size_t)head * CTX * HHD;
#pragma unroll
  for (int i = 0; i < 4; ++i)
    tile[tr + i*8][tc] = ip[(c0 + tr + i*8) * HHD + (d0 + tc)];
  __syncthreads();
#pragma unroll
  for (int i = 0; i < 4; ++i)
    op[(d0 + tr + i*8) * CTX + (c0 + tc)] = tile[tc][tr + i*8];
}

// ---------------- GEMM: C[M][N] = A[M][K](bf16) * Bt[N][K]^T(bf16) + bias ----------------
// m97 structure: global_load_lds staging, 2-barrier K-loop.
// EPI 0: scatter qkv -> Q(pre-scaled 1/8)/K/V [b,h,c,d] bf16
// EPI 1: outf = acc + bias + res (fp32)
// EPI 2: outb = bf16(gelu_exact(acc + bias))
template<int EPI, int BM>
__launch_bounds__(256, 2)
__global__ void k_gemm_bt(const unsigned short* __restrict__ A,
                          const unsigned short* __restrict__ Bt,
                          const float* __restrict__ bias,
                          const float* __restrict__ res,
                          float* __restrict__ outf,
                          unsigned short* __restrict__ outb,
                          unsigned short* __restrict__ outQ,
                          unsigned short* __restrict__ outK,
                          unsigned short* __restrict__ outV,
                          int Ndim, int Kdim) {
  constexpr int WM = 4;
  constexpr int WN = (BM == 128) ? 4 : 2;
  __shared__ __align__(16) unsigned short As[BM * 32];
  __shared__ __align__(16) unsigned short Bs[128 * 32];
  const int m0 = blockIdx.y * BM, n0 = blockIdx.x * 128;
  const int t = threadIdx.x;
  const int w = t >> 6, lane = t & 63, lr = lane & 15, lg = lane >> 4;
  const int wr = (BM == 128) ? (w >> 1) * 64 : 0;
  const int wc = (BM == 128) ? (w & 1) * 64 : w * 32;

  f32x4 acc[WM][WN];
#pragma unroll
  for (int i = 0; i < WM; ++i)
#pragma unroll
    for (int j = 0; j < WN; ++j) acc[i][j] = f32x4{0.f, 0.f, 0.f, 0.f};

  const unsigned short* Ag0 = A  + (size_t)(m0 + (t >> 2)) * Kdim + (t & 3) * 8;
  const unsigned short* Ag1 = A  + (size_t)(m0 + 64 + (t >> 2)) * Kdim + (t & 3) * 8;
  const unsigned short* Bg0 = Bt + (size_t)(n0 + (t >> 2)) * Kdim + (t & 3) * 8;
  const unsigned short* Bg1 = Bt + (size_t)(n0 + 64 + (t >> 2)) * Kdim + (t & 3) * 8;

  const int nk = Kdim >> 5;
  for (int kk = 0; kk < nk; ++kk) {
    const int ko = kk * 32;
    gload16(Ag0 + ko, &As[t * 8]);
    if constexpr (BM == 128) gload16(Ag1 + ko, &As[(256 + t) * 8]);
    gload16(Bg0 + ko, &Bs[t * 8]);
    gload16(Bg1 + ko, &Bs[(256 + t) * 8]);
    __syncthreads();   // drains vmcnt: staged tile visible
    bf16x8 af[WM], bfr[WN];
#pragma unroll
    for (int mi = 0; mi < WM; ++mi)
      af[mi] = *(const bf16x8*)&As[(wr + mi*16 + lr) * 32 + lg * 8];
#pragma unroll
    for (int ni = 0; ni < WN; ++ni)
      bfr[ni] = *(const bf16x8*)&Bs[(wc + ni*16 + lr) * 32 + lg * 8];
#pragma unroll
    for (int mi = 0; mi < WM; ++mi)
#pragma unroll
      for (int ni = 0; ni < WN; ++ni)
        acc[mi][ni] = __builtin_amdgcn_mfma_f32_16x16x32_bf16(af[mi], bfr[ni], acc[mi][ni], 0, 0, 0);
    __syncthreads();   // LDS safe to overwrite
  }

#pragma unroll
  for (int mi = 0; mi < WM; ++mi) {
#pragma unroll
    for (int r = 0; r < 4; ++r) {
      int row = m0 + wr + mi*16 + lg*4 + r;
#pragma unroll
      for (int ni = 0; ni < WN; ++ni) {
        int col = n0 + wc + ni*16 + lr;
        float v = acc[mi][ni][r] + bias[col];
        if constexpr (EPI == 0) {
          int b = row >> 11, c = row & 2047;
          int sec = col >> 10, nn = col & 1023;
          int h = nn >> 6, d = nn & 63;
          size_t o = ((size_t)(b * NH + h) * CTX + c) * HHD + d;
          if (sec == 0) outQ[o] = f2bf(v * 0.125f);     // fold 1/sqrt(HD) into Q
          else if (sec == 1) outK[o] = f2bf(v);
          else outV[o] = f2bf(v);
        } else if constexpr (EPI == 1) {
          size_t o = (size_t)row * Ndim + col;
          outf[o] = v + res[o];
        } else {
          float g = 0.5f * v * (1.0f + erff(v * 0.70710678118654752f));
          outb[(size_t)row * Ndim + col] = f2bf(g);
        }
      }
    }
  }
}

// ---------------- flash attention (swapped-operand form) ----------------
// grid: BB*NH*(CTX/64); block 256 (4 waves); each wave one 16-row Q tile.
// QK^T computed as mfma(K,Q) and PV as mfma(V^T,P): every lane owns exactly one
// q-row (i = lane&15), so softmax max/sum are register trees + 2 shuffles, and
// m/l/alpha apply to oacc without any cross-lane redistribution.
// K,V tiles staged block-wide in LDS via global_load_lds with inverse-swizzled
// SOURCE addresses (linear dest, XOR-swizzled read: 128B rows need it).
__launch_bounds__(256, 2)
__global__ void k_attn(const unsigned short* __restrict__ Qb,
                       const unsigned short* __restrict__ Kb,
                       const unsigned short* __restrict__ Vt,
                       unsigned short* __restrict__ A2) {
  __shared__ __align__(16) unsigned short Ks[64 * 64];   // [j][d], 16B granule G^=(row&7)
  __shared__ __align__(16) unsigned short Vs[64 * 64];   // [d][j], same swizzle
  __shared__ __align__(16) unsigned short pls[4][16 * 64]; // per-wave P [i][j], same swizzle
  const int blk = blockIdx.x;
  const int bh = blk >> 5;        // CTX/64 = 32 q-tiles per (b,h)
  const int qt = blk & 31;
  const int b = bh >> 4, h = bh & 15;
  const int t = threadIdx.x, w = t >> 6, lane = t & 63, lr = lane & 15, lg = lane >> 4;
  const int qbase = qt * 64 + w * 16;
  const unsigned short* Qh = Qb + (size_t)bh * CTX * HHD;
  const unsigned short* Kh = Kb + (size_t)bh * CTX * HHD;
  const unsigned short* Vh = Vt + (size_t)bh * CTX * HHD;
  unsigned short* pw = pls[w];

  // staging source pointers (chunk = 16B granule; row = t>>3, granule = (t&7)^(row&7))
  const int srow = t >> 3, sgr = (t & 7) ^ ((t >> 3) & 7);
  const unsigned short* Kg0 = Kh + srow * HHD + sgr * 8;       // rows 0..31 of tile
  const unsigned short* Kg1 = Kg0 + 32 * HHD;                  // rows 32..63
  const unsigned short* Vg0 = Vh + (size_t)srow * CTX + sgr * 8;
  const unsigned short* Vg1 = Vg0 + (size_t)32 * CTX;

  // Q fragment (B operand): Q[qbase+lr][kc*32+lg*8 ..+8], pre-scaled by 1/8 in G1
  bf16x8 aq[2];
#pragma unroll
  for (int kc = 0; kc < 2; ++kc)
    aq[kc] = *(const bf16x8*)(Qh + (qbase + lr) * HHD + kc * 32 + lg * 8);

  float mrun = -1e30f, lrun = 0.f;   // per-lane scalars for q-row lr (replicated over lg)
  f32x4 oacc[4];                     // oacc[nt][r] = O^T[d = nt*16+lg*4+r][i = qbase+lr]
#pragma unroll
  for (int nt = 0; nt < 4; ++nt) oacc[nt] = f32x4{0.f, 0.f, 0.f, 0.f};

  for (int j0 = 0; j0 < CTX; j0 += 64) {
    gload16(Kg0 + j0 * HHD, &Ks[t * 8]);
    gload16(Kg1 + j0 * HHD, &Ks[(256 + t) * 8]);
    gload16(Vg0 + j0, &Vs[t * 8]);
    gload16(Vg1 + j0, &Vs[(256 + t) * 8]);
    __syncthreads();

    // S^T tile: s[nt][r] = S[j = j0+nt*16+lg*4+r][i = qbase+lr]
    f32x4 s[4];
#pragma unroll
    for (int nt = 0; nt < 4; ++nt) {
      s[nt] = f32x4{0.f, 0.f, 0.f, 0.f};
#pragma unroll
      for (int kc = 0; kc < 2; ++kc) {
        bf16x8 kf = *(const bf16x8*)&Ks[(nt*16 + lr) * 64 + (((kc*4 + lg) ^ (lr & 7)) * 8)];
        s[nt] = __builtin_amdgcn_mfma_f32_16x16x32_bf16(kf, aq[kc], s[nt], 0, 0, 0);
      }
    }

    // row max: register tree (depth 4) + 2 shuffles across the 4 lane-copies of the row
    f32x4 mm;
#pragma unroll
    for (int r = 0; r < 4; ++r)
      mm[r] = fmaxf(fmaxf(s[0][r], s[1][r]), fmaxf(s[2][r], s[3][r]));
    float m = fmaxf(fmaxf(mm[0], mm[1]), fmaxf(mm[2], mm[3]));
    m = fmaxf(m, __shfl_xor(m, 16));
    m = fmaxf(m, __shfl_xor(m, 32));
    float mn = fmaxf(mrun, m);
    float alpha = __expf(mrun - mn);
    mrun = mn;

#pragma unroll
    for (int nt = 0; nt < 4; ++nt)
#pragma unroll
      for (int r = 0; r < 4; ++r)
        s[nt][r] = __expf(s[nt][r] - mn);
    f32x4 s4 = (s[0] + s[1]) + (s[2] + s[3]);
    float sum = (s4[0] + s4[1]) + (s4[2] + s4[3]);
    sum += __shfl_xor(sum, 16);
    sum += __shfl_xor(sum, 32);
    lrun = lrun * alpha + sum;
#pragma unroll
    for (int nt = 0; nt < 4; ++nt) oacc[nt] *= alpha;

    // P -> LDS: lane holds P[i=lr][j=nt*16+lg*4 ..+4]; pack 4 bf16, swizzled 16B granules
#pragma unroll
    for (int nt = 0; nt < 4; ++nt) {
      uint2 pk;
      pk.x = (unsigned)f2bf(s[nt][0]) | ((unsigned)f2bf(s[nt][1]) << 16);
      pk.y = (unsigned)f2bf(s[nt][2]) | ((unsigned)f2bf(s[nt][3]) << 16);
      int G = nt * 2 + (lg >> 1);
      *(uint2*)&pw[lr * 64 + ((G ^ (lr & 7)) * 8) + (lg & 1) * 4] = pk;
    }
    // P fragment (B operand of PV): P[i=lr][j=kc*32+lg*8 ..+8]
    bf16x8 pf[2];
#pragma unroll
    for (int kc = 0; kc < 2; ++kc)
      pf[kc] = *(const bf16x8*)&pw[lr * 64 + (((kc*4 + lg) ^ (lr & 7)) * 8)];
    // PV: oacc[nt] += mfma(V^T-frag, P-frag)
#pragma unroll
    for (int nt = 0; nt < 4; ++nt) {
#pragma unroll
      for (int kc = 0; kc < 2; ++kc) {
        bf16x8 vf = *(const bf16x8*)&Vs[(nt*16 + lr) * 64 + (((kc*4 + lg) ^ (lr & 7)) * 8)];
        oacc[nt] = __builtin_amdgcn_mfma_f32_16x16x32_bf16(vf, pf[kc], oacc[nt], 0, 0, 0);
      }
    }
    __syncthreads();
  }

  float rinv = 1.0f / lrun;
  size_t rowoff = ((size_t)(b * CTX + qbase + lr)) * DDIM + h * HHD;
#pragma unroll
  for (int nt = 0; nt < 4; ++nt) {
    uint2 ov;
    ov.x = (unsigned)f2bf(oacc[nt][0] * rinv) | ((unsigned)f2bf(oacc[nt][1] * rinv) << 16);
    ov.y = (unsigned)f2bf(oacc[nt][2] * rinv) | ((unsigned)f2bf(oacc[nt][3] * rinv) << 16);
    *(uint2*)&A2[rowoff + nt * 16 + lg * 4] = ov;
  }
}

// ---------------- LayerNorm (ddof=1) ----------------
template<bool WB>
__global__ void k_ln(const float* __restrict__ in, const float* __restrict__ gamma,
                     const float* __restrict__ beta, float* __restrict__ outf,
                     unsigned short* __restrict__ outb) {
  const int row = blockIdx.x, t = threadIdx.x;
  const float* x = in + (size_t)row * DDIM;
  float v[4]; float s = 0.f, sq = 0.f;
#pragma unroll
  for (int i = 0; i < 4; ++i) { v[i] = x[t + i*256]; s += v[i]; sq += v[i]*v[i]; }
#pragma unroll
  for (int off = 1; off < 64; off <<= 1) { s += __shfl_xor(s, off); sq += __shfl_xor(sq, off); }
  __shared__ float red[2][4];
  int w = t >> 6;
  if ((t & 63) == 0) { red[0][w] = s; red[1][w] = sq; }
  __syncthreads();
  s  = red[0][0] + red[0][1] + red[0][2] + red[0][3];
  sq = red[1][0] + red[1][1] + red[1][2] + red[1][3];
  float mean = s * (1.0f / DDIM);
  float var  = (sq - s * mean) * (1.0f / (DDIM - 1));
  float rstd = rsqrtf(var + 1e-5f);
#pragma unroll
  for (int i = 0; i < 4; ++i) {
    int c = t + i*256;
    float o = (v[i] - mean) * rstd * gamma[c] + beta[c];
    outf[(size_t)row * DDIM + c] = o;
    if constexpr (WB) outb[(size_t)row * DDIM + c] = f2bf(o);
  }
}

extern "C" void kernel_launch(void* const* d_in, const int* in_sizes, int n_in,
                              void* d_out, int out_size, void* d_ws, size_t ws_size,
                              hipStream_t stream) {
  const float* x      = (const float*)d_in[0];
  const float* w_qkv  = (const float*)d_in[1];
  const float* b_qkv  = (const float*)d_in[2];
  const float* w_out  = (const float*)d_in[3];
  const float* b_out  = (const float*)d_in[4];
  const float* w_ff1  = (const float*)d_in[5];
  const float* b_ff1  = (const float*)d_in[6];
  const float* w_ff2  = (const float*)d_in[7];
  const float* b_ff2  = (const float*)d_in[8];
  const float* gamma1 = (const float*)d_in[9];
  const float* beta1  = (const float*)d_in[10];
  const float* gamma2 = (const float*)d_in[11];
  const float* beta2  = (const float*)d_in[12];
  float* out = (float*)d_out;

  char* ws = (char*)d_ws;
  const size_t MB = 1024ull * 1024ull;
  unsigned short* Xb    = (unsigned short*)(ws + 0);        // 8 MB
  unsigned short* WqkvT = (unsigned short*)(ws + 8*MB);     // 6 MB
  unsigned short* WoutT = (unsigned short*)(ws + 14*MB);    // 2 MB
  unsigned short* Wff1T = (unsigned short*)(ws + 16*MB);    // 8 MB
  unsigned short* Wff2T = (unsigned short*)(ws + 24*MB);    // 8 MB
  unsigned short* Qb    = (unsigned short*)(ws + 32*MB);    // 8 MB
  unsigned short* Kb    = (unsigned short*)(ws + 40*MB);    // 8 MB
  unsigned short* Vt    = (unsigned short*)(ws + 48*MB);    // 8 MB
  unsigned short* A2    = (unsigned short*)(ws + 56*MB);    // 8 MB
  unsigned short* Vb    = (unsigned short*)(ws + 56*MB);    // aliases A2 (dead before attn writes)
  unsigned short* G     = (unsigned short*)(ws + 32*MB);    // 32 MB, reuses Qb..A2 after attn+G2
  float* y1             = (float*)(ws + 64*MB);             // 16 MB
  float* z              = (float*)(ws + 64*MB);             // aliases y1 (dead after LN1)
  float* h1f            = (float*)(ws + 80*MB);             // 16 MB
  unsigned short* h1b   = (unsigned short*)(ws + 96*MB);    // 8 MB  -> total 104 MB

  // bf16 conversions / weight transposes
  k_cvt_bf16<<<dim3(MROWS*DDIM/4/256), dim3(256), 0, stream>>>(x, Xb, MROWS*DDIM/4);
  k_transpose_w<<<dim3(D3/32,  DDIM/32), dim3(256), 0, stream>>>(w_qkv, WqkvT, DDIM, D3);
  k_transpose_w<<<dim3(DDIM/32, DDIM/32), dim3(256), 0, stream>>>(w_out, WoutT, DDIM, DDIM);
  k_transpose_w<<<dim3(DF/32,  DDIM/32), dim3(256), 0, stream>>>(w_ff1, Wff1T, DDIM, DF);
  k_transpose_w<<<dim3(DDIM/32, DF/32),  dim3(256), 0, stream>>>(w_ff2, Wff2T, DF, DDIM);

  // G1: qkv = Xb @ w_qkv + b_qkv  -> Q(1/8),K [b,h,c,d]; V -> Vb [b,h,c,d]
  k_gemm_bt<0,128><<<dim3(D3/128, MROWS/128), dim3(256), 0, stream>>>(
      Xb, WqkvT, b_qkv, nullptr, nullptr, nullptr, Qb, Kb, Vb, D3, DDIM);
  k_transpose_v<<<dim3(HHD/32, CTX/32, BB*NH), dim3(256), 0, stream>>>(Vb, Vt);

  k_attn<<<dim3(BB*NH*(CTX/64)), dim3(256), 0, stream>>>(Qb, Kb, Vt, A2);

  // G2: y1 = A2 @ w_out + b_out + x
  k_gemm_bt<1,64><<<dim3(DDIM/128, MROWS/64), dim3(256), 0, stream>>>(
      A2, WoutT, b_out, x, y1, nullptr, nullptr, nullptr, nullptr, DDIM, DDIM);
  k_ln<true><<<dim3(MROWS), dim3(256), 0, stream>>>(y1, gamma1, beta1, h1f, h1b);

  // G3: G = gelu(h1 @ w_ff1 + b_ff1) bf16
  k_gemm_bt<2,128><<<dim3(DF/128, MROWS/128), dim3(256), 0, stream>>>(
      h1b, Wff1T, b_ff1, nullptr, nullptr, G, nullptr, nullptr, nullptr, DF, DDIM);
  // G4: z = G @ w_ff2 + b_ff2 + h1
  k_gemm_bt<1,64><<<dim3(DDIM/128, MROWS/64), dim3(256), 0, stream>>>(
      G, Wff2T, b_ff2, h1f, z, nullptr, nullptr, nullptr, nullptr, DDIM, DF);
  k_ln<false><<<dim3(MROWS), dim3(256), 0, stream>>>(z, gamma2, beta2, out, nullptr);
}

// Round 3
// 273.181 us; speedup vs baseline: 1.6160x; 1.1097x over previous
//
#include <hip/hip_runtime.h>
#include <hip/hip_bf16.h>
#include <math.h>

#define DDIM 1024
#define HHD  64
#define NH   16
#define BB   2
#define CTX  2048
#define MROWS (BB*CTX)   // 4096
#define D3   (3*DDIM)    // 3072
#define DF   (4*DDIM)    // 4096

using bf16x8 = __attribute__((ext_vector_type(8))) short;
using f32x4  = __attribute__((ext_vector_type(4))) float;

__device__ __forceinline__ unsigned short f2bf(float f) {
  union { float f; unsigned u; } c; c.f = f;
  unsigned u = c.u;
  return (unsigned short)((u + 0x7FFFu + ((u >> 16) & 1u)) >> 16);
}

// packed f32 pair -> bf16x2 (v_cvt_pk_bf16_f32 via compiler)
__device__ __forceinline__ unsigned pk2(float a, float b) {
  __hip_bfloat162 h = __float22bfloat162_rn(float2{a, b});
  return *reinterpret_cast<unsigned*>(&h);
}

// async global->LDS, 16B per lane. LDS dest is wave-uniform base + lane*16.
__device__ __forceinline__ void gload16(const void* g, void* l) {
  __builtin_amdgcn_global_load_lds(
      (const __attribute__((address_space(1))) unsigned int*)g,
      (__attribute__((address_space(3))) unsigned int*)l, 16, 0, 0);
}

// ---------------- elementwise fp32 -> bf16 ----------------
__global__ void k_cvt_bf16(const float* __restrict__ in, unsigned short* __restrict__ out, int n4) {
  int i = blockIdx.x * blockDim.x + threadIdx.x;
  if (i >= n4) return;
  float4 v = reinterpret_cast<const float4*>(in)[i];
  uint2 o;
  o.x = pk2(v.x, v.y); o.y = pk2(v.z, v.w);
  reinterpret_cast<uint2*>(out)[i] = o;
}

// ---------------- transpose fp32 [R][Cn] -> bf16 [Cn][R] ----------------
__global__ void k_transpose_w(const float* __restrict__ in, unsigned short* __restrict__ out,
                              int R, int Cn) {
  __shared__ float tile[32][33];
  int c0 = blockIdx.x * 32, r0 = blockIdx.y * 32;
  int t = threadIdx.x, tr = t >> 5, tc = t & 31;
#pragma unroll
  for (int i = 0; i < 4; ++i)
    tile[tr + i*8][tc] = in[(size_t)(r0 + tr + i*8) * Cn + (c0 + tc)];
  __syncthreads();
#pragma unroll
  for (int i = 0; i < 4; ++i)
    out[(size_t)(c0 + tr + i*8) * R + (r0 + tc)] = f2bf(tile[tc][tr + i*8]);
}

// ------------- per-head bf16 transpose [CTX][HHD] -> [HHD][CTX] -------------
__global__ void k_transpose_v(const unsigned short* __restrict__ in, unsigned short* __restrict__ out) {
  __shared__ unsigned short tile[32][33];
  int head = blockIdx.z;
  int d0 = blockIdx.x * 32, c0 = blockIdx.y * 32;
  int t = threadIdx.x, tr = t >> 5, tc = t & 31;
  const unsigned short* ip = in + (size_t)head * CTX * HHD;
  unsigned short* op = out + (size_t)head * CTX * HHD;
#pragma unroll
  for (int i = 0; i < 4; ++i)
    tile[tr + i*8][tc] = ip[(c0 + tr + i*8) * HHD + (d0 + tc)];
  __syncthreads();
#pragma unroll
  for (int i = 0; i < 4; ++i)
    op[(d0 + tr + i*8) * CTX + (c0 + tc)] = tile[tc][tr + i*8];
}

// ---------------- GEMM: C[M][N] = A[M][K](bf16) * Bt[N][K]^T(bf16) + bias ----------------
// 2-phase double-buffered LDS (stage-next-at-top, one __syncthreads per K-step).
// LDS granule swizzle g ^= (row>>1)&3 applied on BOTH the global source address
// (inverse, staged via global_load_lds linear dest) and the ds_read offset ->
// fragment reads hit 8 distinct bank groups (2-way = free).
// EPI 0: scatter qkv -> Q(pre-scaled 0.125*log2e)/K/V [b,h,c,d] bf16
// EPI 1: outf = acc + bias + res (fp32)
// EPI 2: outb = bf16(gelu_exact(acc + bias))
template<int EPI, int BM>
__launch_bounds__(256, (BM == 128) ? 3 : 4)
__global__ void k_gemm_bt(const unsigned short* __restrict__ A,
                          const unsigned short* __restrict__ Bt,
                          const float* __restrict__ bias,
                          const float* __restrict__ res,
                          float* __restrict__ outf,
                          unsigned short* __restrict__ outb,
                          unsigned short* __restrict__ outQ,
                          unsigned short* __restrict__ outK,
                          unsigned short* __restrict__ outV,
                          int Ndim, int Kdim) {
  constexpr int WM = 4;
  constexpr int WN = (BM == 128) ? 4 : 2;
  __shared__ __align__(16) unsigned short As[2][BM * 32];
  __shared__ __align__(16) unsigned short Bs[2][128 * 32];

  // bijective XCD-chunked swizzle (all grids have nwg % 8 == 0)
  const int nwg = gridDim.x * gridDim.y;
  const int lin = blockIdx.y * gridDim.x + blockIdx.x;
  const int swz = (lin & 7) * (nwg >> 3) + (lin >> 3);
  const int m0 = (swz / gridDim.x) * BM, n0 = (swz % gridDim.x) * 128;

  const int t = threadIdx.x;
  const int w = t >> 6, lane = t & 63, lr = lane & 15, lg = lane >> 4;
  const int wr = (BM == 128) ? (w >> 1) * 64 : 0;
  const int wc = (BM == 128) ? (w & 1) * 64 : w * 32;

  f32x4 acc[WM][WN];
#pragma unroll
  for (int i = 0; i < WM; ++i)
#pragma unroll
    for (int j = 0; j < WN; ++j) acc[i][j] = f32x4{0.f, 0.f, 0.f, 0.f};

  // staging: thread t fills LDS granule t (row=t>>2, g=t&3); source granule = g ^ ((row>>1)&3)
  const int srow = t >> 2;
  const int sgr  = (t & 3) ^ ((t >> 3) & 3);
  const unsigned short* Ag0 = A  + (size_t)(m0 + srow) * Kdim + sgr * 8;
  const unsigned short* Ag1 = Ag0 + (size_t)64 * Kdim;
  const unsigned short* Bg0 = Bt + (size_t)(n0 + srow) * Kdim + sgr * 8;
  const unsigned short* Bg1 = Bg0 + (size_t)64 * Kdim;

  // fragment LDS offsets (loop-invariant, swizzled)
  int offA[WM], offB[WN];
#pragma unroll
  for (int mi = 0; mi < WM; ++mi) {
    int r = wr + mi*16 + lr;
    offA[mi] = r * 32 + ((lg ^ ((r >> 1) & 3)) * 8);
  }
#pragma unroll
  for (int ni = 0; ni < WN; ++ni) {
    int r = wc + ni*16 + lr;
    offB[ni] = r * 32 + ((lg ^ ((r >> 1) & 3)) * 8);
  }

#define STAGE(buf, ko)                                              \
  do {                                                              \
    gload16(Ag0 + (ko), &As[buf][t * 8]);                           \
    if constexpr (BM == 128) gload16(Ag1 + (ko), &As[buf][(256 + t) * 8]); \
    gload16(Bg0 + (ko), &Bs[buf][t * 8]);                           \
    gload16(Bg1 + (ko), &Bs[buf][(256 + t) * 8]);                   \
  } while (0)

  STAGE(0, 0);
  __syncthreads();

  const int nk = Kdim >> 5;
  int cur = 0;
  for (int kk = 0; kk < nk; ++kk) {
    if (kk + 1 < nk) STAGE(cur ^ 1, (kk + 1) * 32);
    bf16x8 af[WM], bfr[WN];
#pragma unroll
    for (int mi = 0; mi < WM; ++mi) af[mi]  = *(const bf16x8*)&As[cur][offA[mi]];
#pragma unroll
    for (int ni = 0; ni < WN; ++ni) bfr[ni] = *(const bf16x8*)&Bs[cur][offB[ni]];
#pragma unroll
    for (int mi = 0; mi < WM; ++mi)
#pragma unroll
      for (int ni = 0; ni < WN; ++ni)
        acc[mi][ni] = __builtin_amdgcn_mfma_f32_16x16x32_bf16(af[mi], bfr[ni], acc[mi][ni], 0, 0, 0);
    __syncthreads();   // drains this iter's stage (latency hidden under MFMA)
    cur ^= 1;
  }
#undef STAGE

#pragma unroll
  for (int mi = 0; mi < WM; ++mi) {
#pragma unroll
    for (int r = 0; r < 4; ++r) {
      int row = m0 + wr + mi*16 + lg*4 + r;
#pragma unroll
      for (int ni = 0; ni < WN; ++ni) {
        int col = n0 + wc + ni*16 + lr;
        float v = acc[mi][ni][r] + bias[col];
        if constexpr (EPI == 0) {
          int b = row >> 11, c = row & 2047;
          int sec = col >> 10, nn = col & 1023;
          int h = nn >> 6, d = nn & 63;
          size_t o = ((size_t)(b * NH + h) * CTX + c) * HHD + d;
          if (sec == 0) outQ[o] = f2bf(v * 0.18033688f);  // 1/8 * log2(e)
          else if (sec == 1) outK[o] = f2bf(v);
          else outV[o] = f2bf(v);
        } else if constexpr (EPI == 1) {
          size_t o = (size_t)row * Ndim + col;
          outf[o] = v + res[o];
        } else {
          float g = 0.5f * v * (1.0f + erff(v * 0.70710678118654752f));
          outb[(size_t)row * Ndim + col] = f2bf(g);
        }
      }
    }
  }
}

// ---------------- flash attention (swapped-operand, exp2 domain) ----------------
// grid: BB*NH*(CTX/64) XCD-swizzled; block 256 (4 waves); wave = one 16-row Q tile.
// mfma(K,Q) / mfma(V^T,P): lane owns q-row i=lane&15 -> softmax is register math.
// Defer-max (THR=8 in log2 units): most tiles skip rescale AND cross-lane max.
// Per-lane partial l-sum, reduced once at the end. K/V double-buffered.
__launch_bounds__(256, 4)
__global__ void k_attn(const unsigned short* __restrict__ Qb,
                       const unsigned short* __restrict__ Kb,
                       const unsigned short* __restrict__ Vt,
                       unsigned short* __restrict__ A2) {
  __shared__ __align__(16) unsigned short Ks[2][64 * 64];
  __shared__ __align__(16) unsigned short Vs[2][64 * 64];
  __shared__ __align__(16) unsigned short pls[4][16 * 64];
  const int lin = blockIdx.x;                    // nwg = 1024
  const int blk = (lin & 7) * 128 + (lin >> 3);  // XCD-chunked: 4 heads per XCD
  const int bh = blk >> 5;
  const int qt = blk & 31;
  const int b = bh >> 4, h = bh & 15;
  const int t = threadIdx.x, w = t >> 6, lane = t & 63, lr = lane & 15, lg = lane >> 4;
  const int qbase = qt * 64 + w * 16;
  const unsigned short* Qh = Qb + (size_t)bh * CTX * HHD;
  const unsigned short* Kh = Kb + (size_t)bh * CTX * HHD;
  const unsigned short* Vh = Vt + (size_t)bh * CTX * HHD;
  unsigned short* pw = pls[w];

  const int srow = t >> 3, sgr = (t & 7) ^ ((t >> 3) & 7);
  const unsigned short* Kg0 = Kh + srow * HHD + sgr * 8;
  const unsigned short* Kg1 = Kg0 + 32 * HHD;
  const unsigned short* Vg0 = Vh + (size_t)srow * CTX + sgr * 8;
  const unsigned short* Vg1 = Vg0 + (size_t)32 * CTX;

#define STAGEKV(buf, j0)                              \
  do {                                                \
    gload16(Kg0 + (j0) * HHD, &Ks[buf][t * 8]);       \
    gload16(Kg1 + (j0) * HHD, &Ks[buf][(256 + t) * 8]); \
    gload16(Vg0 + (j0), &Vs[buf][t * 8]);             \
    gload16(Vg1 + (j0), &Vs[buf][(256 + t) * 8]);     \
  } while (0)

  STAGEKV(0, 0);

  bf16x8 aq[2];
#pragma unroll
  for (int kc = 0; kc < 2; ++kc)
    aq[kc] = *(const bf16x8*)(Qh + (qbase + lr) * HHD + kc * 32 + lg * 8);

  __syncthreads();

  float mrun = -1e30f, lsum = 0.f;
  f32x4 oacc[4];
#pragma unroll
  for (int nt = 0; nt < 4; ++nt) oacc[nt] = f32x4{0.f, 0.f, 0.f, 0.f};

  int cur = 0;
  for (int j0 = 0; j0 < CTX; j0 += 64) {
    if (j0 + 64 < CTX) STAGEKV(cur ^ 1, j0 + 64);

    f32x4 s[4];
#pragma unroll
    for (int nt = 0; nt < 4; ++nt) {
      s[nt] = f32x4{0.f, 0.f, 0.f, 0.f};
#pragma unroll
      for (int kc = 0; kc < 2; ++kc) {
        bf16x8 kf = *(const bf16x8*)&Ks[cur][(nt*16 + lr) * 64 + (((kc*4 + lg) ^ (lr & 7)) * 8)];
        s[nt] = __builtin_amdgcn_mfma_f32_16x16x32_bf16(kf, aq[kc], s[nt], 0, 0, 0);
      }
    }

    // per-lane partial max over this lane's 16 scores (log2 domain)
    f32x4 m4;
#pragma unroll
    for (int r = 0; r < 4; ++r)
      m4[r] = fmaxf(fmaxf(s[0][r], s[1][r]), fmaxf(s[2][r], s[3][r]));
    float pm = fmaxf(fmaxf(m4[0], m4[1]), fmaxf(m4[2], m4[3]));
    if (__any(pm - mrun > 8.0f)) {   // slow path: real max grew
      float m = pm;
      m = fmaxf(m, __shfl_xor(m, 16));
      m = fmaxf(m, __shfl_xor(m, 32));
      float mn = fmaxf(mrun, m);
      float alpha = __builtin_amdgcn_exp2f(mrun - mn);
      mrun = mn;
      lsum *= alpha;
#pragma unroll
      for (int nt = 0; nt < 4; ++nt) oacc[nt] *= alpha;
    }
#pragma unroll
    for (int nt = 0; nt < 4; ++nt)
#pragma unroll
      for (int r = 0; r < 4; ++r)
        s[nt][r] = __builtin_amdgcn_exp2f(s[nt][r] - mrun);
    f32x4 s4 = (s[0] + s[1]) + (s[2] + s[3]);
    lsum += (s4[0] + s4[1]) + (s4[2] + s4[3]);

    // P -> wave-private LDS (packed via cvt_pk), swizzled 16B granules
#pragma unroll
    for (int nt = 0; nt < 4; ++nt) {
      uint2 pk;
      pk.x = pk2(s[nt][0], s[nt][1]);
      pk.y = pk2(s[nt][2], s[nt][3]);
      int G = nt * 2 + (lg >> 1);
      *(uint2*)&pw[lr * 64 + ((G ^ (lr & 7)) * 8) + (lg & 1) * 4] = pk;
    }
    bf16x8 pf[2];
#pragma unroll
    for (int kc = 0; kc < 2; ++kc)
      pf[kc] = *(const bf16x8*)&pw[lr * 64 + (((kc*4 + lg) ^ (lr & 7)) * 8)];
#pragma unroll
    for (int nt = 0; nt < 4; ++nt) {
#pragma unroll
      for (int kc = 0; kc < 2; ++kc) {
        bf16x8 vf = *(const bf16x8*)&Vs[cur][(nt*16 + lr) * 64 + (((kc*4 + lg) ^ (lr & 7)) * 8)];
        oacc[nt] = __builtin_amdgcn_mfma_f32_16x16x32_bf16(vf, pf[kc], oacc[nt], 0, 0, 0);
      }
    }
    __syncthreads();   // next K/V tile staged (hidden under softmax+PV)
    cur ^= 1;
  }
#undef STAGEKV

  lsum += __shfl_xor(lsum, 16);
  lsum += __shfl_xor(lsum, 32);
  float rinv = 1.0f / lsum;
  size_t rowoff = ((size_t)(b * CTX + qbase + lr)) * DDIM + h * HHD;
#pragma unroll
  for (int nt = 0; nt < 4; ++nt) {
    uint2 ov;
    ov.x = pk2(oacc[nt][0] * rinv, oacc[nt][1] * rinv);
    ov.y = pk2(oacc[nt][2] * rinv, oacc[nt][3] * rinv);
    *(uint2*)&A2[rowoff + nt * 16 + lg * 4] = ov;
  }
}

// ---------------- LayerNorm (ddof=1), float4-vectorized ----------------
template<bool WB>
__global__ void k_ln(const float* __restrict__ in, const float* __restrict__ gamma,
                     const float* __restrict__ beta, float* __restrict__ outf,
                     unsigned short* __restrict__ outb) {
  const int row = blockIdx.x, t = threadIdx.x;
  float4 v = reinterpret_cast<const float4*>(in + (size_t)row * DDIM)[t];
  float s  = (v.x + v.y) + (v.z + v.w);
  float sq = (v.x*v.x + v.y*v.y) + (v.z*v.z + v.w*v.w);
#pragma unroll
  for (int off = 1; off < 64; off <<= 1) { s += __shfl_xor(s, off); sq += __shfl_xor(sq, off); }
  __shared__ float red[2][4];
  int w = t >> 6;
  if ((t & 63) == 0) { red[0][w] = s; red[1][w] = sq; }
  __syncthreads();
  s  = red[0][0] + red[0][1] + red[0][2] + red[0][3];
  sq = red[1][0] + red[1][1] + red[1][2] + red[1][3];
  float mean = s * (1.0f / DDIM);
  float var  = (sq - s * mean) * (1.0f / (DDIM - 1));
  float rstd = rsqrtf(var + 1e-5f);
  float4 gm = reinterpret_cast<const float4*>(gamma)[t];
  float4 bt = reinterpret_cast<const float4*>(beta)[t];
  float4 o;
  o.x = (v.x - mean) * rstd * gm.x + bt.x;
  o.y = (v.y - mean) * rstd * gm.y + bt.y;
  o.z = (v.z - mean) * rstd * gm.z + bt.z;
  o.w = (v.w - mean) * rstd * gm.w + bt.w;
  reinterpret_cast<float4*>(outf + (size_t)row * DDIM)[t] = o;
  if constexpr (WB) {
    uint2 p; p.x = pk2(o.x, o.y); p.y = pk2(o.z, o.w);
    reinterpret_cast<uint2*>(outb + (size_t)row * DDIM)[t] = p;
  }
}

extern "C" void kernel_launch(void* const* d_in, const int* in_sizes, int n_in,
                              void* d_out, int out_size, void* d_ws, size_t ws_size,
                              hipStream_t stream) {
  const float* x      = (const float*)d_in[0];
  const float* w_qkv  = (const float*)d_in[1];
  const float* b_qkv  = (const float*)d_in[2];
  const float* w_out  = (const float*)d_in[3];
  const float* b_out  = (const float*)d_in[4];
  const float* w_ff1  = (const float*)d_in[5];
  const float* b_ff1  = (const float*)d_in[6];
  const float* w_ff2  = (const float*)d_in[7];
  const float* b_ff2  = (const float*)d_in[8];
  const float* gamma1 = (const float*)d_in[9];
  const float* beta1  = (const float*)d_in[10];
  const float* gamma2 = (const float*)d_in[11];
  const float* beta2  = (const float*)d_in[12];
  float* out = (float*)d_out;

  char* ws = (char*)d_ws;
  const size_t MB = 1024ull * 1024ull;
  unsigned short* Xb    = (unsigned short*)(ws + 0);        // 8 MB
  unsigned short* WqkvT = (unsigned short*)(ws + 8*MB);     // 6 MB
  unsigned short* WoutT = (unsigned short*)(ws + 14*MB);    // 2 MB
  unsigned short* Wff1T = (unsigned short*)(ws + 16*MB);    // 8 MB
  unsigned short* Wff2T = (unsigned short*)(ws + 24*MB);    // 8 MB
  unsigned short* Qb    = (unsigned short*)(ws + 32*MB);    // 8 MB
  unsigned short* Kb    = (unsigned short*)(ws + 40*MB);    // 8 MB
  unsigned short* Vt    = (unsigned short*)(ws + 48*MB);    // 8 MB
  unsigned short* A2    = (unsigned short*)(ws + 56*MB);    // 8 MB
  unsigned short* Vb    = (unsigned short*)(ws + 56*MB);    // aliases A2 (dead before attn writes)
  unsigned short* G     = (unsigned short*)(ws + 32*MB);    // 32 MB, reuses Qb..A2 after attn+G2
  float* y1             = (float*)(ws + 64*MB);             // 16 MB
  float* z              = (float*)(ws + 64*MB);             // aliases y1 (dead after LN1)
  float* h1f            = (float*)(ws + 80*MB);             // 16 MB
  unsigned short* h1b   = (unsigned short*)(ws + 96*MB);    // 8 MB  -> total 104 MB

  k_cvt_bf16<<<dim3(MROWS*DDIM/4/256), dim3(256), 0, stream>>>(x, Xb, MROWS*DDIM/4);
  k_transpose_w<<<dim3(D3/32,  DDIM/32), dim3(256), 0, stream>>>(w_qkv, WqkvT, DDIM, D3);
  k_transpose_w<<<dim3(DDIM/32, DDIM/32), dim3(256), 0, stream>>>(w_out, WoutT, DDIM, DDIM);
  k_transpose_w<<<dim3(DF/32,  DDIM/32), dim3(256), 0, stream>>>(w_ff1, Wff1T, DDIM, DF);
  k_transpose_w<<<dim3(DDIM/32, DF/32),  dim3(256), 0, stream>>>(w_ff2, Wff2T, DF, DDIM);

  // G1: qkv = Xb @ w_qkv + b_qkv -> Q(*0.125*log2e),K [b,h,c,d]; V -> Vb
  k_gemm_bt<0,128><<<dim3(D3/128, MROWS/128), dim3(256), 0, stream>>>(
      Xb, WqkvT, b_qkv, nullptr, nullptr, nullptr, Qb, Kb, Vb, D3, DDIM);
  k_transpose_v<<<dim3(HHD/32, CTX/32, BB*NH), dim3(256), 0, stream>>>(Vb, Vt);

  k_attn<<<dim3(BB*NH*(CTX/64)), dim3(256), 0, stream>>>(Qb, Kb, Vt, A2);

  // G2: y1 = A2 @ w_out + b_out + x
  k_gemm_bt<1,64><<<dim3(DDIM/128, MROWS/64), dim3(256), 0, stream>>>(
      A2, WoutT, b_out, x, y1, nullptr, nullptr, nullptr, nullptr, DDIM, DDIM);
  k_ln<true><<<dim3(MROWS), dim3(256), 0, stream>>>(y1, gamma1, beta1, h1f, h1b);

  // G3: G = gelu(h1 @ w_ff1 + b_ff1) bf16
  k_gemm_bt<2,128><<<dim3(DF/128, MROWS/128), dim3(256), 0, stream>>>(
      h1b, Wff1T, b_ff1, nullptr, nullptr, G, nullptr, nullptr, nullptr, DF, DDIM);
  // G4: z = G @ w_ff2 + b_ff2 + h1
  k_gemm_bt<1,64><<<dim3(DDIM/128, MROWS/64), dim3(256), 0, stream>>>(
      G, Wff2T, b_ff2, h1f, z, nullptr, nullptr, nullptr, nullptr, DDIM, DF);
  k_ln<false><<<dim3(MROWS), dim3(256), 0, stream>>>(z, gamma2, beta2, out, nullptr);
}